// Round 7
// baseline (685.291 us; speedup 1.0000x reference)
//
#include <hip/hip_runtime.h>
#include <hip/hip_bf16.h>
#include <stdint.h>

#define C_   192
#define H_   256
#define W_   256
#define HW_  65536
#define CHW  12582912
#define NH_  6
#define HID_ 384

typedef __attribute__((ext_vector_type(8))) __bf16 bf16x8;
typedef __attribute__((ext_vector_type(8))) uint16_t u16x8;
typedef __attribute__((ext_vector_type(4))) float  fx4;

__device__ __forceinline__ uint16_t f2bf(float f) {
  uint32_t u = __builtin_bit_cast(uint32_t, f);
  u += 0x7fffu + ((u >> 16) & 1u);
  return (uint16_t)(u >> 16);
}
__device__ __forceinline__ float bf2f(uint16_t h) {
  uint32_t u = ((uint32_t)h) << 16;
  return __builtin_bit_cast(float, u);
}
__device__ __forceinline__ uint32_t pk2(float a, float b) {
  return (uint32_t)f2bf(a) | ((uint32_t)f2bf(b) << 16);
}
__device__ __forceinline__ bf16x8 ld8(const uint16_t* p) {
  uint4 v = *reinterpret_cast<const uint4*>(p);
  return __builtin_bit_cast(bf16x8, v);
}
__device__ __forceinline__ fx4 mfma16(bf16x8 a, bf16x8 b, fx4 c) {
  return __builtin_amdgcn_mfma_f32_16x16x32_bf16(a, b, c, 0, 0, 0);
}
// tanh-form GELU (exp2-based); max |err| vs erf-GELU ~3e-4 (passed absmax rounds 2-6).
__device__ __forceinline__ float gelu_f(float v) {
  float c2 = v * v;
  float u = __builtin_fmaf(c2, 0.044715f, 1.0f) * v;
  float e = exp2f(u * 2.3022084f);
  float th = 1.0f - 2.0f * __builtin_amdgcn_rcpf(1.0f + e);
  float hv = 0.5f * v;
  return __builtin_fmaf(hv, th, hv);
}

// ---------------- K0: weight prep (r0 version: plain transposes, no LN fold) ----------------
__global__ __launch_bounds__(256) void prep_kernel(
    const float* __restrict__ qkv_w, const float* __restrict__ proj_w,
    const float* __restrict__ fc1_w, const float* __restrict__ fc2_w,
    const float* __restrict__ rpb,
    uint16_t* __restrict__ qkv_wt, uint16_t* __restrict__ proj_wt,
    uint16_t* __restrict__ fc1_wt, uint16_t* __restrict__ fc2_wt,
    float* __restrict__ rpbb) {
  int tid = blockIdx.x * 256 + threadIdx.x;
  if (tid < 576 * 192) {
    int f = tid / 192, k = tid % 192;
    qkv_wt[tid] = f2bf(qkv_w[k * 576 + f]);
  }
  int t1 = tid - 576 * 192;
  if (t1 >= 0 && t1 < 192 * 192) {
    int f = t1 / 192, k = t1 % 192;
    proj_wt[t1] = f2bf(proj_w[k * 192 + f]);
  }
  int t2 = t1 - 192 * 192;
  if (t2 >= 0 && t2 < 384 * 192) {
    int f = t2 / 192, k = t2 % 192;
    fc1_wt[t2] = f2bf(fc1_w[k * 384 + f]);
  }
  int t3 = t2 - 384 * 192;
  if (t3 >= 0 && t3 < 192 * 384) {
    int f = t3 / 384, k = t3 % 384;
    fc2_wt[t3] = f2bf(fc2_w[k * 192 + f]);
  }
  int t4 = t3 - 192 * 384;
  if (t4 >= 0 && t4 < 6 * 64 * 64) {
    int h = t4 / 4096, nm = t4 % 4096, n = nm / 64, m = nm % 64;
    int yn = n >> 3, xn = n & 7, ym = m >> 3, xm = m & 7;
    int idx = (yn - ym + 7) * 15 + (xn - xm + 7);
    rpbb[t4] = rpb[idx * NH_ + h];
  }
}

// ---------------- K1a: LN1 stats ----------------
__global__ __launch_bounds__(256) void ln1_stats(const float* __restrict__ x,
                                                 float* __restrict__ mu,
                                                 float* __restrict__ rsig) {
  int t = blockIdx.x * 256 + threadIdx.x;
  int b = t >> 16, hw = t & 65535;
  const float* xp = x + (size_t)b * CHW + hw;
  float s = 0.f, sq = 0.f;
#pragma unroll 8
  for (int c = 0; c < C_; c++) {
    float v = xp[(size_t)c * HW_];
    s += v; sq += v * v;
  }
  float m = s * (1.0f / C_);
  float var = sq * (1.0f / C_) - m * m;
  mu[t] = m;
  rsig[t] = rsqrtf(var + 1e-6f);
}

// ---------------- K1b: apply LN1 + roll shuffle -> token-major bf16 ----------------
__global__ __launch_bounds__(256) void ln1_apply_kernel(
    const float* __restrict__ x, const float* __restrict__ mu, const float* __restrict__ rsig,
    const float* __restrict__ n1w, const float* __restrict__ n1b,
    uint16_t* __restrict__ y_tok) {
  __shared__ __attribute__((aligned(16))) uint16_t tile[192 * 66];
  int wg = blockIdx.x;
  int b = wg >> 10, hw0 = (wg & 1023) << 6;
  int t = threadIdx.x;
  const float* xb = x + (size_t)b * CHW;
  const float* mub = mu + b * HW_;
  const float* rsb = rsig + b * HW_;
#pragma unroll 4
  for (int it = 0; it < 48; it++) {
    int id = it * 256 + t;
    int ca = id >> 6, pp = id & 63;
    int g = ca * 65536 + hw0 + pp;
    int h2 = g / 49152;
    int r = g - h2 * 49152;
    int w2 = r / 192;
    int c2 = r - w2 * 192;
    int f = ((h2 + 4) & 255) * 49152 + ((w2 + 4) & 255) * 192 + c2;
    int cnat = f >> 16;
    int hwn = f & 65535;
    float v = (xb[f] - mub[hwn]) * rsb[hwn] * n1w[cnat] + n1b[cnat];
    tile[ca * 66 + pp] = f2bf(v);
  }
  __syncthreads();
  uint16_t* yb = y_tok + ((size_t)(b * HW_ + hw0)) * C_;
#pragma unroll 4
  for (int it = 0; it < 48; it++) {
    int id = it * 256 + t;
    int pp = id / 192, ca = id - pp * 192;
    yb[id] = tile[ca * 66 + pp];
  }
}

// ---------------- K2: fused window attention + GAP partials (r0 proven) ----------------
__global__ __launch_bounds__(256, 2) void attn_kernel(
    const uint16_t* __restrict__ y_tok, const uint16_t* __restrict__ qkv_wt,
    const float* __restrict__ qkv_b, const uint16_t* __restrict__ proj_wt,
    const float* __restrict__ proj_b, const float* __restrict__ rpbb,
    uint16_t* __restrict__ y_attn, float* __restrict__ part) {
  __shared__ __attribute__((aligned(16))) uint16_t Qs[64 * 200];
  __shared__ __attribute__((aligned(16))) uint16_t Ks[64 * 200];
  __shared__ __attribute__((aligned(16))) uint16_t VT[32 * 72];
  __shared__ __attribute__((aligned(16))) uint16_t Ps[64 * 72];
  const int wg = blockIdx.x;
  const int b = wg >> 10, wid = wg & 1023;
  const int wh = wid >> 5, ww = wid & 31;
  const int t = threadIdx.x;
  const int w = t >> 6, l = t & 63;
  const int lane16 = l & 15, quad = l >> 4;
  const int trow = w * 16 + quad * 4;

  bf16x8 afr[4][6];
#pragma unroll
  for (int m = 0; m < 4; m++) {
    const int tok = m * 16 + lane16;
    const uint16_t* ap = y_tok +
        ((size_t)(b * HW_ + (wh * 8 + (tok >> 3)) * W_ + ww * 8 + (tok & 7))) * C_ + quad * 8;
#pragma unroll
    for (int k = 0; k < 6; k++) afr[m][k] = ld8(ap + k * 32);
  }

  const float scale = 0.17677669529663687f;
  uint32_t vpack[3][4][2];

#pragma unroll
  for (int j = 0; j < 3; j++) {
    const int nt = w + 4 * j;
    const uint16_t* bp = qkv_wt + (nt * 16 + lane16) * C_ + quad * 8;
    bf16x8 bfr[6];
#pragma unroll
    for (int k = 0; k < 6; k++) bfr[k] = ld8(bp + k * 32);
    fx4 acc[4];
#pragma unroll
    for (int m = 0; m < 4; m++) acc[m] = fx4{0.f, 0.f, 0.f, 0.f};
#pragma unroll
    for (int k = 0; k < 6; k++)
#pragma unroll
      for (int m = 0; m < 4; m++) acc[m] = mfma16(afr[m][k], bfr[k], acc[m]);
    const int f = nt * 16 + lane16;
    const float bias = qkv_b[f];
#pragma unroll
    for (int m = 0; m < 4; m++)
#pragma unroll
      for (int r = 0; r < 4; r++)
        Qs[(m * 16 + quad * 4 + r) * 200 + f] = f2bf((acc[m][r] + bias) * scale);
  }
#pragma unroll
  for (int j = 3; j < 6; j++) {
    const int nt = w + 4 * j;
    const uint16_t* bp = qkv_wt + (nt * 16 + lane16) * C_ + quad * 8;
    bf16x8 bfr[6];
#pragma unroll
    for (int k = 0; k < 6; k++) bfr[k] = ld8(bp + k * 32);
    fx4 acc[4];
#pragma unroll
    for (int m = 0; m < 4; m++) acc[m] = fx4{0.f, 0.f, 0.f, 0.f};
#pragma unroll
    for (int k = 0; k < 6; k++)
#pragma unroll
      for (int m = 0; m < 4; m++) acc[m] = mfma16(afr[m][k], bfr[k], acc[m]);
    const int f = nt * 16 + lane16;
    const float bias = qkv_b[f];
#pragma unroll
    for (int m = 0; m < 4; m++)
#pragma unroll
      for (int r = 0; r < 4; r++)
        Ks[(m * 16 + quad * 4 + r) * 200 + (f - 192)] = f2bf(acc[m][r] + bias);
  }
#pragma unroll
  for (int j = 6; j < 9; j++) {
    const int nt = w + 4 * j;
    const uint16_t* bp = qkv_wt + (nt * 16 + lane16) * C_ + quad * 8;
    bf16x8 bfr[6];
#pragma unroll
    for (int k = 0; k < 6; k++) bfr[k] = ld8(bp + k * 32);
    fx4 acc[4];
#pragma unroll
    for (int m = 0; m < 4; m++) acc[m] = fx4{0.f, 0.f, 0.f, 0.f};
#pragma unroll
    for (int k = 0; k < 6; k++)
#pragma unroll
      for (int m = 0; m < 4; m++) acc[m] = mfma16(afr[m][k], bfr[k], acc[m]);
    const float bias = qkv_b[nt * 16 + lane16];
    const int jv = j - 6;
#pragma unroll
    for (int m = 0; m < 4; m++) {
      vpack[jv][m][0] = pk2(acc[m][0] + bias, acc[m][1] + bias);
      vpack[jv][m][1] = pk2(acc[m][2] + bias, acc[m][3] + bias);
    }
  }

  const bool whe = (wh == 31), wwe = (ww == 31);

  for (int h = 0; h < 6; h++) {
    __syncthreads();
    {
      const int vt0 = 2 * h, vt1 = 2 * h + 1;
      if (w == (vt0 & 3)) {
        const int jv = vt0 >> 2;
#pragma unroll
        for (int m = 0; m < 4; m++) {
          uint2 vv; vv.x = vpack[jv][m][0]; vv.y = vpack[jv][m][1];
          *reinterpret_cast<uint2*>(&VT[lane16 * 72 + m * 16 + quad * 4]) = vv;
        }
      }
      if (w == (vt1 & 3)) {
        const int jv = vt1 >> 2;
#pragma unroll
        for (int m = 0; m < 4; m++) {
          uint2 vv; vv.x = vpack[jv][m][0]; vv.y = vpack[jv][m][1];
          *reinterpret_cast<uint2*>(&VT[(16 + lane16) * 72 + m * 16 + quad * 4]) = vv;
        }
      }
    }
    __syncthreads();

    const bf16x8 qa = ld8(&Qs[(w * 16 + lane16) * 200 + h * 32 + quad * 8]);
    fx4 sacc[4];
#pragma unroll
    for (int nt = 0; nt < 4; nt++) {
      const bf16x8 kb = ld8(&Ks[(nt * 16 + lane16) * 200 + h * 32 + quad * 8]);
      fx4 z = {0.f, 0.f, 0.f, 0.f};
      sacc[nt] = mfma16(qa, kb, z);
    }
    const float* rb = rpbb + h * 4096;
#pragma unroll
    for (int nt = 0; nt < 4; nt++) {
      const int ct = nt * 16 + lane16;
      const bool rbc = whe && ((ct >> 3) >= 4);
      const bool cbc = wwe && ((ct & 7) >= 4);
#pragma unroll
      for (int r = 0; r < 4; r++) {
        const int rt = trow + r;
        const bool rbr = whe && ((rt >> 3) >= 4);
        const bool cbr = wwe && ((rt & 7) >= 4);
        float v = sacc[nt][r] + rb[rt * 64 + ct];
        if (rbr != rbc || cbr != cbc) v -= 100.f;
        sacc[nt][r] = v;
      }
    }
    float sm[4];
#pragma unroll
    for (int r = 0; r < 4; r++) {
      float m = fmaxf(fmaxf(sacc[0][r], sacc[1][r]), fmaxf(sacc[2][r], sacc[3][r]));
      m = fmaxf(m, __shfl_xor(m, 1));
      m = fmaxf(m, __shfl_xor(m, 2));
      m = fmaxf(m, __shfl_xor(m, 4));
      m = fmaxf(m, __shfl_xor(m, 8));
      float s0 = 0.f;
#pragma unroll
      for (int nt = 0; nt < 4; nt++) {
        float e = exp2f((sacc[nt][r] - m) * 1.4426950408889634f);
        sacc[nt][r] = e; s0 += e;
      }
      s0 += __shfl_xor(s0, 1);
      s0 += __shfl_xor(s0, 2);
      s0 += __shfl_xor(s0, 4);
      s0 += __shfl_xor(s0, 8);
      sm[r] = s0;
    }
#pragma unroll
    for (int nt = 0; nt < 4; nt++)
#pragma unroll
      for (int r = 0; r < 4; r++)
        Ps[(trow + r) * 72 + nt * 16 + lane16] = f2bf(sacc[nt][r]);
    fx4 o0 = {0.f, 0.f, 0.f, 0.f}, o1 = {0.f, 0.f, 0.f, 0.f};
#pragma unroll
    for (int ks2 = 0; ks2 < 2; ks2++) {
      const bf16x8 pa = ld8(&Ps[(w * 16 + lane16) * 72 + ks2 * 32 + quad * 8]);
      const bf16x8 v0 = ld8(&VT[(lane16) * 72 + ks2 * 32 + quad * 8]);
      const bf16x8 v1 = ld8(&VT[(16 + lane16) * 72 + ks2 * 32 + quad * 8]);
      o0 = mfma16(pa, v0, o0);
      o1 = mfma16(pa, v1, o1);
    }
#pragma unroll
    for (int r = 0; r < 4; r++) {
      const float inv = 1.0f / sm[r];
      Qs[(trow + r) * 200 + h * 32 + lane16] = f2bf(o0[r] * inv);
      Qs[(trow + r) * 200 + h * 32 + 16 + lane16] = f2bf(o1[r] * inv);
    }
  }
  __syncthreads();

  bf16x8 ofr[4][6];
#pragma unroll
  for (int m = 0; m < 4; m++)
#pragma unroll
    for (int k = 0; k < 6; k++)
      ofr[m][k] = ld8(&Qs[(m * 16 + lane16) * 200 + k * 32 + quad * 8]);

  uint16_t* yb = y_attn + (size_t)b * HW_ * C_;
  uint32_t obase[4][4];
#pragma unroll
  for (int m = 0; m < 4; m++)
#pragma unroll
    for (int r = 0; r < 4; r++) {
      const int tok = m * 16 + quad * 4 + r;
      obase[m][r] = (uint32_t)(((wh * 8 + (tok >> 3)) * W_ + ww * 8 + (tok & 7)) * C_);
    }
#pragma unroll
  for (int j = 0; j < 3; j++) {
    const int nt = w + 4 * j;
    const uint16_t* bp = proj_wt + (nt * 16 + lane16) * C_ + quad * 8;
    bf16x8 bfr[6];
#pragma unroll
    for (int k = 0; k < 6; k++) bfr[k] = ld8(bp + k * 32);
    fx4 acc[4];
#pragma unroll
    for (int m = 0; m < 4; m++) acc[m] = fx4{0.f, 0.f, 0.f, 0.f};
#pragma unroll
    for (int k = 0; k < 6; k++)
#pragma unroll
      for (int m = 0; m < 4; m++) acc[m] = mfma16(ofr[m][k], bfr[k], acc[m]);
    const float pb = proj_b[nt * 16 + lane16];
    float cs = 0.f;
#pragma unroll
    for (int m = 0; m < 4; m++)
#pragma unroll
      for (int r = 0; r < 4; r++) {
        const float v = acc[m][r] + pb;
        yb[obase[m][r] + nt * 16 + lane16] = f2bf(v);
        cs += v;
      }
    cs += __shfl_xor(cs, 16);
    cs += __shfl_xor(cs, 32);
    if (l < 16) part[(size_t)wg * 192 + nt * 16 + lane16] = cs;
  }
}

// ---------------- K3a: gap partial reduce (128 blocks instead of 2) ----------------
__global__ __launch_bounds__(192) void ca_gap(const float* __restrict__ part,
                                              float* __restrict__ gpart) {
  int blk = blockIdx.x;            // 128 = 2 b x 64 chunks
  int b = blk >> 6, ch = blk & 63;
  int c = threadIdx.x;             // 192
  float s = 0.f;
#pragma unroll
  for (int i = 0; i < 16; i++)
    s += part[((size_t)b * 1024 + ch * 16 + i) * 192 + c];
  gpart[blk * 192 + c] = s;
}

// ---------------- K3b: final gap + channel-attention matvec ----------------
__global__ __launch_bounds__(192) void ca_s2(const float* __restrict__ gpart,
                                             const float* __restrict__ ca_w,
                                             const float* __restrict__ ca_b,
                                             float* __restrict__ sbuf) {
  int b = blockIdx.x;
  int t = threadIdx.x;             // 192
  __shared__ float gap[192];
  float s = 0.f;
#pragma unroll 8
  for (int i = 0; i < 64; i++) s += gpart[(b * 64 + i) * 192 + t];
  gap[t] = s * (1.0f / 65536.0f);
  __syncthreads();
  float acc = ca_b[t];
#pragma unroll 8
  for (int c2 = 0; c2 < 192; c2++) acc += gap[c2] * ca_w[t * 192 + c2];
  sbuf[b * 192 + t] = acc;
}

// ---------------- K4: resid + LN2 -> token-major bf16 t2 (r0 proven) ----------------
__global__ __launch_bounds__(256, 3) void resid_ln2(
    const float* __restrict__ x, const uint16_t* __restrict__ y_attn,
    const float* __restrict__ sbuf, const float* __restrict__ n2w,
    const float* __restrict__ n2b, uint16_t* __restrict__ t2) {
  __shared__ __attribute__((aligned(16))) float tile[192 * 66];
  __shared__ float red[512];
  __shared__ float mus[128];
  int wg = blockIdx.x;
  int b = wg >> 10, hw0 = (wg & 1023) << 6;
  int t = threadIdx.x;
#pragma unroll 4
  for (int it = 0; it < 48; it++) {
    int id = it * 256 + t;
    int c = id >> 6, p = id & 63;
    tile[c * 66 + p] = x[(size_t)b * CHW + (size_t)c * HW_ + hw0 + p];
  }
  __syncthreads();
#pragma unroll 4
  for (int it = 0; it < 48; it++) {
    int id = it * 256 + t;
    int p = id / 192, c = id - p * 192;
    float y = bf2f(y_attn[((size_t)(b * HW_ + hw0 + p)) * C_ + c]);
    tile[c * 66 + p] += sbuf[b * 192 + c] * y;
  }
  __syncthreads();
  {
    int p = t & 63, g = t >> 6;
    float s = 0.f, sq = 0.f;
    for (int c = g * 48; c < g * 48 + 48; c++) {
      float v = tile[c * 66 + p];
      s += v; sq += v * v;
    }
    red[g * 64 + p] = s;
    red[256 + g * 64 + p] = sq;
  }
  __syncthreads();
  if (t < 64) {
    float ss = red[t] + red[64 + t] + red[128 + t] + red[192 + t];
    float qq = red[256 + t] + red[320 + t] + red[384 + t] + red[448 + t];
    float m = ss * (1.0f / C_);
    float var = qq * (1.0f / C_) - m * m;
    mus[t] = m;
    mus[64 + t] = rsqrtf(var + 1e-6f);
  }
  __syncthreads();
#pragma unroll 4
  for (int it = 0; it < 48; it++) {
    int id = it * 256 + t;
    int p = id / 192, c = id - p * 192;
    float v = (tile[c * 66 + p] - mus[p]) * mus[64 + p] * n2w[c] + n2b[c];
    t2[((size_t)(b * HW_ + hw0 + p)) * C_ + c] = f2bf(v);
  }
}

// ---------------- K5: MLP half-tile (32 px/block, 4096 blocks, ~27 KB LDS, 6 blk/CU) ----
__global__ __launch_bounds__(256, 4) void mlp_kernel(
    const uint16_t* __restrict__ t2, const uint16_t* __restrict__ fc1_wt,
    const float* __restrict__ fc1_b, const uint16_t* __restrict__ fc2_wt,
    const float* __restrict__ fc2_b, const float* __restrict__ x,
    const uint16_t* __restrict__ y_attn, const float* __restrict__ sbuf,
    float* __restrict__ out) {
  __shared__ __attribute__((aligned(16))) char smem[192 * 34 * 4];  // hbuf | ftile (26112 B)
  __shared__ float sarr[192];
  uint16_t* hbuf = (uint16_t*)smem;          // [32][392] bf16 (25088 B)
  float* ftile = (float*)smem;               // [192][34] f32 (aliased after barrier)
  int wg = blockIdx.x;
  int b = wg >> 11, hw0 = (wg & 2047) << 5;
  int t = threadIdx.x;
  int w = t >> 6, l = t & 63;
  int lane16 = l & 15, quad = l >> 4;
  const int m1 = w & 1, ng = w >> 1;
  if (t < 192) sarr[t] = sbuf[b * 192 + t];

  // A frags for 32 tokens (wave owns m-tile m1)
  bf16x8 afr[6];
  {
    const uint16_t* ap = t2 + ((size_t)(b * HW_ + hw0 + m1 * 16 + lane16)) * C_ + quad * 8;
#pragma unroll
    for (int k = 0; k < 6; k++) afr[k] = ld8(ap + k * 32);
  }

  // GEMM1 + GELU -> hbuf; wave owns nt = ng*12 + j  (r0 store idiom)
#pragma unroll 4
  for (int j = 0; j < 12; j++) {
    const int nt = ng * 12 + j;
    const uint16_t* bp = fc1_wt + (nt * 16 + lane16) * C_ + quad * 8;
    bf16x8 bfr[6];
#pragma unroll
    for (int k = 0; k < 6; k++) bfr[k] = ld8(bp + k * 32);
    fx4 acc = {0.f, 0.f, 0.f, 0.f};
#pragma unroll
    for (int k = 0; k < 6; k++) acc = mfma16(afr[k], bfr[k], acc);
    const float bias = fc1_b[nt * 16 + lane16];
#pragma unroll
    for (int r = 0; r < 4; r++) {
      float ge = gelu_f(acc[r] + bias);
      hbuf[(m1 * 16 + quad * 4 + r) * 392 + nt * 16 + lane16] = f2bf(ge);
    }
  }
  __syncthreads();   // hidden features cross-wave

  // GEMM2: wave owns m = m1, nt2 = ng*6 + j (j<6); K in 4x3 chunks
  fx4 acc2[6];
#pragma unroll
  for (int j = 0; j < 6; j++) acc2[j] = fx4{0.f, 0.f, 0.f, 0.f};
#pragma unroll
  for (int kc = 0; kc < 4; kc++) {
#pragma unroll
    for (int kk = 0; kk < 3; kk++) {
      const bf16x8 ha = ld8(&hbuf[(m1 * 16 + lane16) * 392 + kc * 96 + kk * 32 + quad * 8]);
#pragma unroll
      for (int j = 0; j < 6; j++) {
        const int nt2 = ng * 6 + j;
        const bf16x8 bb = ld8(fc2_wt + (nt2 * 16 + lane16) * HID_ + kc * 96 + kk * 32 + quad * 8);
        acc2[j] = mfma16(ha, bb, acc2[j]);
      }
    }
  }
  __syncthreads();   // hbuf dead; ftile aliases

  // y2 + bias -> ftile[o][tok]
#pragma unroll
  for (int j = 0; j < 6; j++) {
    const int nt2 = ng * 6 + j;
    const float bias = fc2_b[nt2 * 16 + lane16];
    float* fp = &ftile[(nt2 * 16 + lane16) * 34 + m1 * 16 + quad * 4];
    float2 aa = {acc2[j][0] + bias, acc2[j][1] + bias};
    float2 bb2 = {acc2[j][2] + bias, acc2[j][3] + bias};
    *reinterpret_cast<float2*>(fp) = aa;
    *reinterpret_cast<float2*>(fp + 2) = bb2;
  }
  __syncthreads();

  // ftile += s[c] * y_attn (8 q-groups x 24 channels, token-major ld8)
  {
    const int p = t & 31, q = t >> 5;
    const uint16_t* yr = y_attn + ((size_t)(b * HW_ + hw0 + p)) * C_;
#pragma unroll
    for (int i = 0; i < 3; i++) {
      int qq = q * 3 + i;
      u16x8 uv = __builtin_bit_cast(u16x8, ld8(yr + qq * 8));
#pragma unroll
      for (int j = 0; j < 8; j++) {
        int c = qq * 8 + j;
        ftile[c * 34 + p] += sarr[c] * bf2f(uv[j]);
      }
    }
  }
  __syncthreads();

  // out = x + ftile (float2 coalesced; 32-px rows = 128B segments)
  const float* xb = x + (size_t)b * CHW + hw0;
  float* ob = out + (size_t)b * CHW + hw0;
#pragma unroll
  for (int i = 0; i < 12; i++) {
    int id = i * 256 + t;
    int c = id >> 4, p2 = id & 15;
    float2 xv = *reinterpret_cast<const float2*>(xb + (size_t)c * HW_ + p2 * 2);
    float2 fv = *reinterpret_cast<const float2*>(&ftile[c * 34 + p2 * 2]);
    float2 ov = {xv.x + fv.x, xv.y + fv.y};
    *reinterpret_cast<float2*>(ob + (size_t)c * HW_ + p2 * 2) = ov;
  }
}

extern "C" void kernel_launch(void* const* d_in, const int* in_sizes, int n_in,
                              void* d_out, int out_size, void* d_ws, size_t ws_size,
                              hipStream_t stream) {
  const float* x      = (const float*)d_in[0];
  const float* n1w    = (const float*)d_in[1];
  const float* n1b    = (const float*)d_in[2];
  const float* qkv_w  = (const float*)d_in[3];
  const float* qkv_b  = (const float*)d_in[4];
  const float* proj_w = (const float*)d_in[5];
  const float* proj_b = (const float*)d_in[6];
  const float* rpb    = (const float*)d_in[7];
  const float* ca_w   = (const float*)d_in[8];
  const float* ca_b   = (const float*)d_in[9];
  const float* n2w    = (const float*)d_in[10];
  const float* n2b    = (const float*)d_in[11];
  const float* fc1_w  = (const float*)d_in[12];
  const float* fc1_b  = (const float*)d_in[13];
  const float* fc2_w  = (const float*)d_in[14];
  const float* fc2_b  = (const float*)d_in[15];
  float* out = (float*)d_out;

  char* ws = (char*)d_ws;
  uint16_t* y_tok   = (uint16_t*)(ws + 0);           // 50331648 B (aliased by t2)
  uint16_t* y_attn  = (uint16_t*)(ws + 50331648);    // 50331648 B
  uint16_t* t2      = y_tok;                         // alias (y_tok dead after attn)
  float*    mu      = (float*)   (ws + 100663296);   // 524288 B
  float*    rsig    = (float*)   (ws + 101187584);   // 524288 B
  uint16_t* qkv_wt  = (uint16_t*)(ws + 101711872);   // 221184 B
  uint16_t* proj_wt = (uint16_t*)(ws + 101933056);   // 73728 B
  uint16_t* fc1_wt  = (uint16_t*)(ws + 102006784);   // 147456 B
  uint16_t* fc2_wt  = (uint16_t*)(ws + 102154240);   // 147456 B
  float*    rpbb    = (float*)   (ws + 102301696);   // 98304 B
  float*    part    = (float*)   (ws + 102400000);   // 1572864 B
  float*    sbuf    = (float*)   (ws + 103972864);   // 1536 B
  float*    gpart   = (float*)   (ws + 103974400);   // 98304 B

  hipLaunchKernelGGL(prep_kernel, dim3(1248), dim3(256), 0, stream,
                     qkv_w, proj_w, fc1_w, fc2_w, rpb, qkv_wt, proj_wt, fc1_wt, fc2_wt, rpbb);
  hipLaunchKernelGGL(ln1_stats, dim3(512), dim3(256), 0, stream, x, mu, rsig);
  hipLaunchKernelGGL(ln1_apply_kernel, dim3(2048), dim3(256), 0, stream,
                     x, mu, rsig, n1w, n1b, y_tok);
  hipLaunchKernelGGL(attn_kernel, dim3(2048), dim3(256), 0, stream,
                     y_tok, qkv_wt, qkv_b, proj_wt, proj_b, rpbb, y_attn, part);
  hipLaunchKernelGGL(ca_gap, dim3(128), dim3(192), 0, stream, part, gpart);
  hipLaunchKernelGGL(ca_s2, dim3(2), dim3(192), 0, stream, gpart, ca_w, ca_b, sbuf);
  hipLaunchKernelGGL(resid_ln2, dim3(2048), dim3(256), 0, stream,
                     x, y_attn, sbuf, n2w, n2b, t2);
  hipLaunchKernelGGL(mlp_kernel, dim3(4096), dim3(256), 0, stream,
                     t2, fc1_wt, fc1_b, fc2_wt, fc2_b, x, y_attn, sbuf, out);
}

// Round 8
// 526.162 us; speedup vs baseline: 1.3024x; 1.3024x over previous
//
#include <hip/hip_runtime.h>
#include <hip/hip_bf16.h>
#include <stdint.h>

#define C_   192
#define H_   256
#define W_   256
#define HW_  65536
#define CHW  12582912
#define NH_  6
#define HID_ 384

typedef __attribute__((ext_vector_type(8))) __bf16 bf16x8;
typedef __attribute__((ext_vector_type(8))) uint16_t u16x8;
typedef __attribute__((ext_vector_type(4))) float  fx4;

__device__ __forceinline__ uint16_t f2bf(float f) {
  uint32_t u = __builtin_bit_cast(uint32_t, f);
  u += 0x7fffu + ((u >> 16) & 1u);
  return (uint16_t)(u >> 16);
}
__device__ __forceinline__ float bf2f(uint16_t h) {
  uint32_t u = ((uint32_t)h) << 16;
  return __builtin_bit_cast(float, u);
}
__device__ __forceinline__ uint32_t pk2(float a, float b) {
  return (uint32_t)f2bf(a) | ((uint32_t)f2bf(b) << 16);
}
__device__ __forceinline__ bf16x8 ld8(const uint16_t* p) {
  uint4 v = *reinterpret_cast<const uint4*>(p);
  return __builtin_bit_cast(bf16x8, v);
}
__device__ __forceinline__ fx4 mfma16(bf16x8 a, bf16x8 b, fx4 c) {
  return __builtin_amdgcn_mfma_f32_16x16x32_bf16(a, b, c, 0, 0, 0);
}
// tanh-form GELU (exp2-based); max |err| vs erf-GELU ~3e-4 (absmax-validated r2-r6).
__device__ __forceinline__ float gelu_f(float v) {
  float c2 = v * v;
  float u = __builtin_fmaf(c2, 0.044715f, 1.0f) * v;
  float e = exp2f(u * 2.3022084f);
  float th = 1.0f - 2.0f * __builtin_amdgcn_rcpf(1.0f + e);
  float hv = 0.5f * v;
  return __builtin_fmaf(hv, th, hv);
}

// ---------------- K0: weight prep ----------------
__global__ __launch_bounds__(256) void prep_kernel(
    const float* __restrict__ qkv_w, const float* __restrict__ proj_w,
    const float* __restrict__ fc1_w, const float* __restrict__ fc2_w,
    const float* __restrict__ rpb,
    uint16_t* __restrict__ qkv_wt, uint16_t* __restrict__ proj_wt,
    uint16_t* __restrict__ fc1_wt, uint16_t* __restrict__ fc2_wt,
    float* __restrict__ rpbb) {
  int tid = blockIdx.x * 256 + threadIdx.x;
  if (tid < 576 * 192) {
    int f = tid / 192, k = tid % 192;
    qkv_wt[tid] = f2bf(qkv_w[k * 576 + f]);
  }
  int t1 = tid - 576 * 192;
  if (t1 >= 0 && t1 < 192 * 192) {
    int f = t1 / 192, k = t1 % 192;
    proj_wt[t1] = f2bf(proj_w[k * 192 + f]);
  }
  int t2 = t1 - 192 * 192;
  if (t2 >= 0 && t2 < 384 * 192) {
    int f = t2 / 192, k = t2 % 192;
    fc1_wt[t2] = f2bf(fc1_w[k * 384 + f]);
  }
  int t3 = t2 - 384 * 192;
  if (t3 >= 0 && t3 < 192 * 384) {
    int f = t3 / 384, k = t3 % 384;
    fc2_wt[t3] = f2bf(fc2_w[k * 192 + f]);
  }
  int t4 = t3 - 192 * 384;
  if (t4 >= 0 && t4 < 6 * 64 * 64) {
    int h = t4 / 4096, nm = t4 % 4096, n = nm / 64, m = nm % 64;
    int yn = n >> 3, xn = n & 7, ym = m >> 3, xm = m & 7;
    int idx = (yn - ym + 7) * 15 + (xn - xm + 7);
    rpbb[t4] = rpb[idx * NH_ + h];
  }
}

// ---------------- K1a: LN1 stats ----------------
__global__ __launch_bounds__(256) void ln1_stats(const float* __restrict__ x,
                                                 float* __restrict__ mu,
                                                 float* __restrict__ rsig) {
  int t = blockIdx.x * 256 + threadIdx.x;
  int b = t >> 16, hw = t & 65535;
  const float* xp = x + (size_t)b * CHW + hw;
  float s = 0.f, sq = 0.f;
#pragma unroll 8
  for (int c = 0; c < C_; c++) {
    float v = xp[(size_t)c * HW_];
    s += v; sq += v * v;
  }
  float m = s * (1.0f / C_);
  float var = sq * (1.0f / C_) - m * m;
  mu[t] = m;
  rsig[t] = rsqrtf(var + 1e-6f);
}

// ---------------- K1b: apply LN1 + roll shuffle -> token-major bf16 ----------------
__global__ __launch_bounds__(256) void ln1_apply_kernel(
    const float* __restrict__ x, const float* __restrict__ mu, const float* __restrict__ rsig,
    const float* __restrict__ n1w, const float* __restrict__ n1b,
    uint16_t* __restrict__ y_tok) {
  __shared__ __attribute__((aligned(16))) uint16_t tile[192 * 66];
  int wg = blockIdx.x;
  int b = wg >> 10, hw0 = (wg & 1023) << 6;
  int t = threadIdx.x;
  const float* xb = x + (size_t)b * CHW;
  const float* mub = mu + b * HW_;
  const float* rsb = rsig + b * HW_;
#pragma unroll 4
  for (int it = 0; it < 48; it++) {
    int id = it * 256 + t;
    int ca = id >> 6, pp = id & 63;
    int g = ca * 65536 + hw0 + pp;
    int h2 = g / 49152;
    int r = g - h2 * 49152;
    int w2 = r / 192;
    int c2 = r - w2 * 192;
    int f = ((h2 + 4) & 255) * 49152 + ((w2 + 4) & 255) * 192 + c2;
    int cnat = f >> 16;
    int hwn = f & 65535;
    float v = (xb[f] - mub[hwn]) * rsb[hwn] * n1w[cnat] + n1b[cnat];
    tile[ca * 66 + pp] = f2bf(v);
  }
  __syncthreads();
  uint16_t* yb = y_tok + ((size_t)(b * HW_ + hw0)) * C_;
#pragma unroll 4
  for (int it = 0; it < 48; it++) {
    int id = it * 256 + t;
    int pp = id / 192, ca = id - pp * 192;
    yb[id] = tile[ca * 66 + pp];
  }
}

// ---------------- K2: fused window attention + GAP partials (r0 proven) ----------------
__global__ __launch_bounds__(256, 2) void attn_kernel(
    const uint16_t* __restrict__ y_tok, const uint16_t* __restrict__ qkv_wt,
    const float* __restrict__ qkv_b, const uint16_t* __restrict__ proj_wt,
    const float* __restrict__ proj_b, const float* __restrict__ rpbb,
    uint16_t* __restrict__ y_attn, float* __restrict__ part) {
  __shared__ __attribute__((aligned(16))) uint16_t Qs[64 * 200];
  __shared__ __attribute__((aligned(16))) uint16_t Ks[64 * 200];
  __shared__ __attribute__((aligned(16))) uint16_t VT[32 * 72];
  __shared__ __attribute__((aligned(16))) uint16_t Ps[64 * 72];
  const int wg = blockIdx.x;
  const int b = wg >> 10, wid = wg & 1023;
  const int wh = wid >> 5, ww = wid & 31;
  const int t = threadIdx.x;
  const int w = t >> 6, l = t & 63;
  const int lane16 = l & 15, quad = l >> 4;
  const int trow = w * 16 + quad * 4;

  bf16x8 afr[4][6];
#pragma unroll
  for (int m = 0; m < 4; m++) {
    const int tok = m * 16 + lane16;
    const uint16_t* ap = y_tok +
        ((size_t)(b * HW_ + (wh * 8 + (tok >> 3)) * W_ + ww * 8 + (tok & 7))) * C_ + quad * 8;
#pragma unroll
    for (int k = 0; k < 6; k++) afr[m][k] = ld8(ap + k * 32);
  }

  const float scale = 0.17677669529663687f;
  uint32_t vpack[3][4][2];

#pragma unroll
  for (int j = 0; j < 3; j++) {
    const int nt = w + 4 * j;
    const uint16_t* bp = qkv_wt + (nt * 16 + lane16) * C_ + quad * 8;
    bf16x8 bfr[6];
#pragma unroll
    for (int k = 0; k < 6; k++) bfr[k] = ld8(bp + k * 32);
    fx4 acc[4];
#pragma unroll
    for (int m = 0; m < 4; m++) acc[m] = fx4{0.f, 0.f, 0.f, 0.f};
#pragma unroll
    for (int k = 0; k < 6; k++)
#pragma unroll
      for (int m = 0; m < 4; m++) acc[m] = mfma16(afr[m][k], bfr[k], acc[m]);
    const int f = nt * 16 + lane16;
    const float bias = qkv_b[f];
#pragma unroll
    for (int m = 0; m < 4; m++)
#pragma unroll
      for (int r = 0; r < 4; r++)
        Qs[(m * 16 + quad * 4 + r) * 200 + f] = f2bf((acc[m][r] + bias) * scale);
  }
#pragma unroll
  for (int j = 3; j < 6; j++) {
    const int nt = w + 4 * j;
    const uint16_t* bp = qkv_wt + (nt * 16 + lane16) * C_ + quad * 8;
    bf16x8 bfr[6];
#pragma unroll
    for (int k = 0; k < 6; k++) bfr[k] = ld8(bp + k * 32);
    fx4 acc[4];
#pragma unroll
    for (int m = 0; m < 4; m++) acc[m] = fx4{0.f, 0.f, 0.f, 0.f};
#pragma unroll
    for (int k = 0; k < 6; k++)
#pragma unroll
      for (int m = 0; m < 4; m++) acc[m] = mfma16(afr[m][k], bfr[k], acc[m]);
    const int f = nt * 16 + lane16;
    const float bias = qkv_b[f];
#pragma unroll
    for (int m = 0; m < 4; m++)
#pragma unroll
      for (int r = 0; r < 4; r++)
        Ks[(m * 16 + quad * 4 + r) * 200 + (f - 192)] = f2bf(acc[m][r] + bias);
  }
#pragma unroll
  for (int j = 6; j < 9; j++) {
    const int nt = w + 4 * j;
    const uint16_t* bp = qkv_wt + (nt * 16 + lane16) * C_ + quad * 8;
    bf16x8 bfr[6];
#pragma unroll
    for (int k = 0; k < 6; k++) bfr[k] = ld8(bp + k * 32);
    fx4 acc[4];
#pragma unroll
    for (int m = 0; m < 4; m++) acc[m] = fx4{0.f, 0.f, 0.f, 0.f};
#pragma unroll
    for (int k = 0; k < 6; k++)
#pragma unroll
      for (int m = 0; m < 4; m++) acc[m] = mfma16(afr[m][k], bfr[k], acc[m]);
    const float bias = qkv_b[nt * 16 + lane16];
    const int jv = j - 6;
#pragma unroll
    for (int m = 0; m < 4; m++) {
      vpack[jv][m][0] = pk2(acc[m][0] + bias, acc[m][1] + bias);
      vpack[jv][m][1] = pk2(acc[m][2] + bias, acc[m][3] + bias);
    }
  }

  const bool whe = (wh == 31), wwe = (ww == 31);

  for (int h = 0; h < 6; h++) {
    __syncthreads();
    {
      const int vt0 = 2 * h, vt1 = 2 * h + 1;
      if (w == (vt0 & 3)) {
        const int jv = vt0 >> 2;
#pragma unroll
        for (int m = 0; m < 4; m++) {
          uint2 vv; vv.x = vpack[jv][m][0]; vv.y = vpack[jv][m][1];
          *reinterpret_cast<uint2*>(&VT[lane16 * 72 + m * 16 + quad * 4]) = vv;
        }
      }
      if (w == (vt1 & 3)) {
        const int jv = vt1 >> 2;
#pragma unroll
        for (int m = 0; m < 4; m++) {
          uint2 vv; vv.x = vpack[jv][m][0]; vv.y = vpack[jv][m][1];
          *reinterpret_cast<uint2*>(&VT[(16 + lane16) * 72 + m * 16 + quad * 4]) = vv;
        }
      }
    }
    __syncthreads();

    const bf16x8 qa = ld8(&Qs[(w * 16 + lane16) * 200 + h * 32 + quad * 8]);
    fx4 sacc[4];
#pragma unroll
    for (int nt = 0; nt < 4; nt++) {
      const bf16x8 kb = ld8(&Ks[(nt * 16 + lane16) * 200 + h * 32 + quad * 8]);
      fx4 z = {0.f, 0.f, 0.f, 0.f};
      sacc[nt] = mfma16(qa, kb, z);
    }
    const float* rb = rpbb + h * 4096;
#pragma unroll
    for (int nt = 0; nt < 4; nt++) {
      const int ct = nt * 16 + lane16;
      const bool rbc = whe && ((ct >> 3) >= 4);
      const bool cbc = wwe && ((ct & 7) >= 4);
#pragma unroll
      for (int r = 0; r < 4; r++) {
        const int rt = trow + r;
        const bool rbr = whe && ((rt >> 3) >= 4);
        const bool cbr = wwe && ((rt & 7) >= 4);
        float v = sacc[nt][r] + rb[rt * 64 + ct];
        if (rbr != rbc || cbr != cbc) v -= 100.f;
        sacc[nt][r] = v;
      }
    }
    float sm[4];
#pragma unroll
    for (int r = 0; r < 4; r++) {
      float m = fmaxf(fmaxf(sacc[0][r], sacc[1][r]), fmaxf(sacc[2][r], sacc[3][r]));
      m = fmaxf(m, __shfl_xor(m, 1));
      m = fmaxf(m, __shfl_xor(m, 2));
      m = fmaxf(m, __shfl_xor(m, 4));
      m = fmaxf(m, __shfl_xor(m, 8));
      float s0 = 0.f;
#pragma unroll
      for (int nt = 0; nt < 4; nt++) {
        float e = exp2f((sacc[nt][r] - m) * 1.4426950408889634f);
        sacc[nt][r] = e; s0 += e;
      }
      s0 += __shfl_xor(s0, 1);
      s0 += __shfl_xor(s0, 2);
      s0 += __shfl_xor(s0, 4);
      s0 += __shfl_xor(s0, 8);
      sm[r] = s0;
    }
#pragma unroll
    for (int nt = 0; nt < 4; nt++)
#pragma unroll
      for (int r = 0; r < 4; r++)
        Ps[(trow + r) * 72 + nt * 16 + lane16] = f2bf(sacc[nt][r]);
    fx4 o0 = {0.f, 0.f, 0.f, 0.f}, o1 = {0.f, 0.f, 0.f, 0.f};
#pragma unroll
    for (int ks2 = 0; ks2 < 2; ks2++) {
      const bf16x8 pa = ld8(&Ps[(w * 16 + lane16) * 72 + ks2 * 32 + quad * 8]);
      const bf16x8 v0 = ld8(&VT[(lane16) * 72 + ks2 * 32 + quad * 8]);
      const bf16x8 v1 = ld8(&VT[(16 + lane16) * 72 + ks2 * 32 + quad * 8]);
      o0 = mfma16(pa, v0, o0);
      o1 = mfma16(pa, v1, o1);
    }
#pragma unroll
    for (int r = 0; r < 4; r++) {
      const float inv = 1.0f / sm[r];
      Qs[(trow + r) * 200 + h * 32 + lane16] = f2bf(o0[r] * inv);
      Qs[(trow + r) * 200 + h * 32 + 16 + lane16] = f2bf(o1[r] * inv);
    }
  }
  __syncthreads();

  bf16x8 ofr[4][6];
#pragma unroll
  for (int m = 0; m < 4; m++)
#pragma unroll
    for (int k = 0; k < 6; k++)
      ofr[m][k] = ld8(&Qs[(m * 16 + lane16) * 200 + k * 32 + quad * 8]);

  uint16_t* yb = y_attn + (size_t)b * HW_ * C_;
  uint32_t obase[4][4];
#pragma unroll
  for (int m = 0; m < 4; m++)
#pragma unroll
    for (int r = 0; r < 4; r++) {
      const int tok = m * 16 + quad * 4 + r;
      obase[m][r] = (uint32_t)(((wh * 8 + (tok >> 3)) * W_ + ww * 8 + (tok & 7)) * C_);
    }
#pragma unroll
  for (int j = 0; j < 3; j++) {
    const int nt = w + 4 * j;
    const uint16_t* bp = proj_wt + (nt * 16 + lane16) * C_ + quad * 8;
    bf16x8 bfr[6];
#pragma unroll
    for (int k = 0; k < 6; k++) bfr[k] = ld8(bp + k * 32);
    fx4 acc[4];
#pragma unroll
    for (int m = 0; m < 4; m++) acc[m] = fx4{0.f, 0.f, 0.f, 0.f};
#pragma unroll
    for (int k = 0; k < 6; k++)
#pragma unroll
      for (int m = 0; m < 4; m++) acc[m] = mfma16(ofr[m][k], bfr[k], acc[m]);
    const float pb = proj_b[nt * 16 + lane16];
    float cs = 0.f;
#pragma unroll
    for (int m = 0; m < 4; m++)
#pragma unroll
      for (int r = 0; r < 4; r++) {
        const float v = acc[m][r] + pb;
        yb[obase[m][r] + nt * 16 + lane16] = f2bf(v);
        cs += v;
      }
    cs += __shfl_xor(cs, 16);
    cs += __shfl_xor(cs, 32);
    if (l < 16) part[(size_t)wg * 192 + nt * 16 + lane16] = cs;
  }
}

// ---------------- K3a: gap partial reduce (parallel) ----------------
__global__ __launch_bounds__(192) void ca_gap(const float* __restrict__ part,
                                              float* __restrict__ gpart) {
  int blk = blockIdx.x;            // 128 = 2 b x 64 chunks
  int b = blk >> 6, ch = blk & 63;
  int c = threadIdx.x;             // 192
  float s = 0.f;
#pragma unroll
  for (int i = 0; i < 16; i++)
    s += part[((size_t)b * 1024 + ch * 16 + i) * 192 + c];
  gpart[blk * 192 + c] = s;
}

// ---------------- K3b: final gap + channel-attention matvec ----------------
__global__ __launch_bounds__(192) void ca_s2(const float* __restrict__ gpart,
                                             const float* __restrict__ ca_w,
                                             const float* __restrict__ ca_b,
                                             float* __restrict__ sbuf) {
  int b = blockIdx.x;
  int t = threadIdx.x;             // 192
  __shared__ float gap[192];
  float s = 0.f;
#pragma unroll 8
  for (int i = 0; i < 64; i++) s += gpart[(b * 64 + i) * 192 + t];
  gap[t] = s * (1.0f / 65536.0f);
  __syncthreads();
  float acc = ca_b[t];
#pragma unroll 8
  for (int c2 = 0; c2 < 192; c2++) acc += gap[c2] * ca_w[t * 192 + c2];
  sbuf[b * 192 + t] = acc;
}

// ---------------- K4: resid + LN2 -> token-major bf16 t2 (r0 proven) ----------------
__global__ __launch_bounds__(256, 3) void resid_ln2(
    const float* __restrict__ x, const uint16_t* __restrict__ y_attn,
    const float* __restrict__ sbuf, const float* __restrict__ n2w,
    const float* __restrict__ n2b, uint16_t* __restrict__ t2) {
  __shared__ __attribute__((aligned(16))) float tile[192 * 66];
  __shared__ float red[512];
  __shared__ float mus[128];
  int wg = blockIdx.x;
  int b = wg >> 10, hw0 = (wg & 1023) << 6;
  int t = threadIdx.x;
#pragma unroll 4
  for (int it = 0; it < 48; it++) {
    int id = it * 256 + t;
    int c = id >> 6, p = id & 63;
    tile[c * 66 + p] = x[(size_t)b * CHW + (size_t)c * HW_ + hw0 + p];
  }
  __syncthreads();
#pragma unroll 4
  for (int it = 0; it < 48; it++) {
    int id = it * 256 + t;
    int p = id / 192, c = id - p * 192;
    float y = bf2f(y_attn[((size_t)(b * HW_ + hw0 + p)) * C_ + c]);
    tile[c * 66 + p] += sbuf[b * 192 + c] * y;
  }
  __syncthreads();
  {
    int p = t & 63, g = t >> 6;
    float s = 0.f, sq = 0.f;
    for (int c = g * 48; c < g * 48 + 48; c++) {
      float v = tile[c * 66 + p];
      s += v; sq += v * v;
    }
    red[g * 64 + p] = s;
    red[256 + g * 64 + p] = sq;
  }
  __syncthreads();
  if (t < 64) {
    float ss = red[t] + red[64 + t] + red[128 + t] + red[192 + t];
    float qq = red[256 + t] + red[320 + t] + red[384 + t] + red[448 + t];
    float m = ss * (1.0f / C_);
    float var = qq * (1.0f / C_) - m * m;
    mus[t] = m;
    mus[64 + t] = rsqrtf(var + 1e-6f);
  }
  __syncthreads();
#pragma unroll 4
  for (int it = 0; it < 48; it++) {
    int id = it * 256 + t;
    int p = id / 192, c = id - p * 192;
    float v = (tile[c * 66 + p] - mus[p]) * mus[64 + p] * n2w[c] + n2b[c];
    t2[((size_t)(b * HW_ + hw0 + p)) * C_ + c] = f2bf(v);
  }
}

// ---------------- K5: MLP (r0 structure; swapped-operand GEMM1 + vector hbuf stores,
//                   tanh GELU). Everything else identical to the 200us r0 kernel. ----
__global__ __launch_bounds__(256, 3) void mlp_kernel(
    const uint16_t* __restrict__ t2, const uint16_t* __restrict__ fc1_wt,
    const float* __restrict__ fc1_b, const uint16_t* __restrict__ fc2_wt,
    const float* __restrict__ fc2_b, const float* __restrict__ x,
    const uint16_t* __restrict__ y_attn, const float* __restrict__ sbuf,
    float* __restrict__ out) {
  __shared__ __attribute__((aligned(16))) char smem[192 * 66 * 4];  // hbuf | ftile
  __shared__ float sarr[192];
  uint16_t* hbuf = (uint16_t*)smem;          // [64][392] bf16
  float* ftile = (float*)smem;               // [192][66] f32 (aliased after barrier)
  int wg = blockIdx.x;
  int b = wg >> 10, hw0 = (wg & 1023) << 6;
  int t = threadIdx.x;
  int w = t >> 6, l = t & 63;
  int lane16 = l & 15, quad = l >> 4;
  if (t < 192) sarr[t] = sbuf[b * 192 + t];

  // A frags for all 64 tokens from token-major t2
  bf16x8 afr[4][6];
  const uint16_t* ab = t2 + ((size_t)(b * HW_ + hw0)) * C_;
#pragma unroll
  for (int m = 0; m < 4; m++) {
    const uint16_t* ap = ab + (m * 16 + lane16) * C_ + quad * 8;
#pragma unroll
    for (int k = 0; k < 6; k++) afr[m][k] = ld8(ap + k * 32);
  }

  // GEMM1 (SWAPPED operands -> D[f][tok]) + tanh GELU -> hbuf
  // wave owns nt = w + 4j, j 0..5; per (j,m): one uint2 LDS store (4 consecutive f)
#pragma unroll
  for (int j = 0; j < 6; j++) {
    const int nt = w + 4 * j;
    const uint16_t* bp = fc1_wt + (nt * 16 + lane16) * C_ + quad * 8;
    bf16x8 bfr[6];
#pragma unroll
    for (int k = 0; k < 6; k++) bfr[k] = ld8(bp + k * 32);
    fx4 acc[4];
#pragma unroll
    for (int m = 0; m < 4; m++) acc[m] = fx4{0.f, 0.f, 0.f, 0.f};
#pragma unroll
    for (int k = 0; k < 6; k++)
#pragma unroll
      for (int m = 0; m < 4; m++) acc[m] = mfma16(bfr[k], afr[m][k], acc[m]);
    const fx4 bv = *reinterpret_cast<const fx4*>(fc1_b + nt * 16 + quad * 4);
#pragma unroll
    for (int m = 0; m < 4; m++) {
      float g0 = gelu_f(acc[m][0] + bv[0]);
      float g1 = gelu_f(acc[m][1] + bv[1]);
      float g2 = gelu_f(acc[m][2] + bv[2]);
      float g3 = gelu_f(acc[m][3] + bv[3]);
      uint2 wv = {pk2(g0, g1), pk2(g2, g3)};
      *reinterpret_cast<uint2*>(&hbuf[(m * 16 + lane16) * 392 + nt * 16 + quad * 4]) = wv;
    }
  }
  __syncthreads();   // hidden features are cross-wave now

  // GEMM2: wave owns nt = w + 4j, j 0..2; hidden A-frags from LDS in 4 k-chunks
  fx4 acc2[3][4];
#pragma unroll
  for (int j = 0; j < 3; j++)
#pragma unroll
    for (int m = 0; m < 4; m++) acc2[j][m] = fx4{0.f, 0.f, 0.f, 0.f};
#pragma unroll
  for (int kc = 0; kc < 4; kc++) {
    bf16x8 ha[4][3];
#pragma unroll
    for (int m = 0; m < 4; m++)
#pragma unroll
      for (int kk = 0; kk < 3; kk++)
        ha[m][kk] = ld8(&hbuf[(m * 16 + lane16) * 392 + kc * 96 + kk * 32 + quad * 8]);
#pragma unroll
    for (int j = 0; j < 3; j++) {
      const int nt = w + 4 * j;
      const uint16_t* bp = fc2_wt + (nt * 16 + lane16) * HID_ + kc * 96 + quad * 8;
#pragma unroll
      for (int kk = 0; kk < 3; kk++) {
        const bf16x8 bb = ld8(bp + kk * 32);
#pragma unroll
        for (int m = 0; m < 4; m++) acc2[j][m] = mfma16(ha[m][kk], bb, acc2[j][m]);
      }
    }
  }
  __syncthreads();   // all hbuf reads done; ftile may alias

  // y2 + bias -> ftile[c][tok] (f32)
#pragma unroll
  for (int j = 0; j < 3; j++) {
    const int nt = w + 4 * j;
    const float bias = fc2_b[nt * 16 + lane16];
#pragma unroll
    for (int m = 0; m < 4; m++) {
      float* fp = &ftile[(nt * 16 + lane16) * 66 + m * 16 + quad * 4];
      float2 a = {acc2[j][m][0] + bias, acc2[j][m][1] + bias};
      float2 b2 = {acc2[j][m][2] + bias, acc2[j][m][3] + bias};
      *reinterpret_cast<float2*>(fp) = a;
      *reinterpret_cast<float2*>(fp + 2) = b2;
    }
  }
  __syncthreads();
  // += s[c] * y_attn (coalesced token-major read)
#pragma unroll 4
  for (int it = 0; it < 48; it++) {
    int id = it * 256 + t;
    int p = id / 192, c = id - p * 192;
    float y = bf2f(y_attn[((size_t)(b * HW_ + hw0 + p)) * C_ + c]);
    ftile[c * 66 + p] += sarr[c] * y;
  }
  __syncthreads();
  // out = x + ftile (BCHW coalesced)
#pragma unroll 4
  for (int it = 0; it < 48; it++) {
    int id = it * 256 + t;
    int c = id >> 6, p = id & 63;
    size_t gi = (size_t)b * CHW + (size_t)c * HW_ + hw0 + p;
    out[gi] = x[gi] + ftile[c * 66 + p];
  }
}

extern "C" void kernel_launch(void* const* d_in, const int* in_sizes, int n_in,
                              void* d_out, int out_size, void* d_ws, size_t ws_size,
                              hipStream_t stream) {
  const float* x      = (const float*)d_in[0];
  const float* n1w    = (const float*)d_in[1];
  const float* n1b    = (const float*)d_in[2];
  const float* qkv_w  = (const float*)d_in[3];
  const float* qkv_b  = (const float*)d_in[4];
  const float* proj_w = (const float*)d_in[5];
  const float* proj_b = (const float*)d_in[6];
  const float* rpb    = (const float*)d_in[7];
  const float* ca_w   = (const float*)d_in[8];
  const float* ca_b   = (const float*)d_in[9];
  const float* n2w    = (const float*)d_in[10];
  const float* n2b    = (const float*)d_in[11];
  const float* fc1_w  = (const float*)d_in[12];
  const float* fc1_b  = (const float*)d_in[13];
  const float* fc2_w  = (const float*)d_in[14];
  const float* fc2_b  = (const float*)d_in[15];
  float* out = (float*)d_out;

  char* ws = (char*)d_ws;
  uint16_t* y_tok   = (uint16_t*)(ws + 0);           // 50331648 B (aliased by t2)
  uint16_t* y_attn  = (uint16_t*)(ws + 50331648);    // 50331648 B
  uint16_t* t2      = y_tok;                         // alias (y_tok dead after attn)
  float*    mu      = (float*)   (ws + 100663296);   // 524288 B
  float*    rsig    = (float*)   (ws + 101187584);   // 524288 B
  uint16_t* qkv_wt  = (uint16_t*)(ws + 101711872);   // 221184 B
  uint16_t* proj_wt = (uint16_t*)(ws + 101933056);   // 73728 B
  uint16_t* fc1_wt  = (uint16_t*)(ws + 102006784);   // 147456 B
  uint16_t* fc2_wt  = (uint16_t*)(ws + 102154240);   // 147456 B
  float*    rpbb    = (float*)   (ws + 102301696);   // 98304 B
  float*    part    = (float*)   (ws + 102400000);   // 1572864 B
  float*    sbuf    = (float*)   (ws + 103972864);   // 1536 B
  float*    gpart   = (float*)   (ws + 103974400);   // 98304 B

  hipLaunchKernelGGL(prep_kernel, dim3(1248), dim3(256), 0, stream,
                     qkv_w, proj_w, fc1_w, fc2_w, rpb, qkv_wt, proj_wt, fc1_wt, fc2_wt, rpbb);
  hipLaunchKernelGGL(ln1_stats, dim3(512), dim3(256), 0, stream, x, mu, rsig);
  hipLaunchKernelGGL(ln1_apply_kernel, dim3(2048), dim3(256), 0, stream,
                     x, mu, rsig, n1w, n1b, y_tok);
  hipLaunchKernelGGL(attn_kernel, dim3(2048), dim3(256), 0, stream,
                     y_tok, qkv_wt, qkv_b, proj_wt, proj_b, rpbb, y_attn, part);
  hipLaunchKernelGGL(ca_gap, dim3(128), dim3(192), 0, stream, part, gpart);
  hipLaunchKernelGGL(ca_s2, dim3(2), dim3(192), 0, stream, gpart, ca_w, ca_b, sbuf);
  hipLaunchKernelGGL(resid_ln2, dim3(2048), dim3(256), 0, stream,
                     x, y_attn, sbuf, n2w, n2b, t2);
  hipLaunchKernelGGL(mlp_kernel, dim3(2048), dim3(256), 0, stream,
                     t2, fc1_wt, fc1_b, fc2_wt, fc2_b, x, y_attn, sbuf, out);
}